// Round 11
// baseline (48.830 us; speedup 1.0000x reference)
//
#include <hip/hip_runtime.h>
#include <stdint.h>

// Problem constants (from setup_inputs in the reference)
#define BB    4
#define NCAM  6
#define HF    64
#define WF    176
#define IMGPIX (HF * WF)               // 11264
#define NIMG  (BB * NCAM)              // 24
#define NPIX  (NIMG * IMGPIX)          // 270336
#define NEDGE 49
#define SENTINEL 0x7F7F7F7F            // fallback path: memset-able, > any label

// ---- f32-semantics toggles (validated: absmax 0 in rounds 4-10) ----
#define GER_FMA     1
#define TRSM_RECIP  1
#define TRSM_FMA    1

// ---------------------------------------------------------------------------
// np.linalg.inv(float32) emulation = LAPACK sgesv(A, I). Validated bit-exact
// (absmax 0, R4-R10). fp contract(off) INSIDE the function (lexically scoped;
// R7 lesson). Runs only in the tiny 24-thread prep kernel — its
// runtime-indexed arrays (scratch) must stay OUT of the hot kernel (R9 lesson).
// ---------------------------------------------------------------------------
__device__ void inv4_sgesv(const float* __restrict__ m,   // 4x4 cam2ego
                           const float* __restrict__ K,   // 3x3 intrinsics
                           float* __restrict__ out) {     // 16 floats
#pragma clang fp contract(off)
    float a[4][4];
    for (int i = 0; i < 4; ++i)
        for (int j = 0; j < 4; ++j)
            a[i][j] = m[i * 4 + j];

    // ---- sgetf2: right-looking LU with partial pivoting ----
    int ipiv[4];
    for (int j = 0; j < 4; ++j) {
        int p = j;
        float best = fabsf(a[j][j]);
        for (int i = j + 1; i < 4; ++i) {
            float v = fabsf(a[i][j]);
            if (v > best) { best = v; p = i; }
        }
        ipiv[j] = p;
        if (p != j) {
            for (int k = 0; k < 4; ++k) {
                float t = a[j][k]; a[j][k] = a[p][k]; a[p][k] = t;
            }
        }
        float r = 1.0f / a[j][j];
        for (int i = j + 1; i < 4; ++i) a[i][j] = a[i][j] * r;
        for (int k = j + 1; k < 4; ++k) {
            float temp = -a[j][k];
            for (int i = j + 1; i < 4; ++i) {
#if GER_FMA
                a[i][k] = __builtin_fmaf(a[i][j], temp, a[i][k]);
#else
                a[i][k] = a[i][k] + a[i][j] * temp;
#endif
            }
        }
    }

    // ---- sgetrs on B = I ----
    float bmat[4][4];
    for (int i = 0; i < 4; ++i)
        for (int j = 0; j < 4; ++j)
            bmat[i][j] = (i == j) ? 1.0f : 0.0f;

    for (int k = 0; k < 4; ++k) {
        int p = ipiv[k];
        if (p != k) {
            for (int c = 0; c < 4; ++c) {
                float t = bmat[k][c]; bmat[k][c] = bmat[p][c]; bmat[p][c] = t;
            }
        }
    }

    // trsm: Left, Lower, NoTrans, Unit
    for (int c = 0; c < 4; ++c) {
        for (int k = 0; k < 4; ++k) {
            float bk = bmat[k][c];
            for (int i = k + 1; i < 4; ++i) {
#if TRSM_FMA
                bmat[i][c] = __builtin_fmaf(a[i][k], -bk, bmat[i][c]);
#else
                bmat[i][c] = bmat[i][c] - a[i][k] * bk;
#endif
            }
        }
    }

    // trsm: Left, Upper, NoTrans, NonUnit (reciprocal diagonal)
#if TRSM_RECIP
    float rdiag[4];
    for (int k = 0; k < 4; ++k) rdiag[k] = 1.0f / a[k][k];
#endif
    for (int c = 0; c < 4; ++c) {
        for (int k = 3; k >= 0; --k) {
#if TRSM_RECIP
            bmat[k][c] = bmat[k][c] * rdiag[k];
#else
            bmat[k][c] = bmat[k][c] / a[k][k];
#endif
            float bk = bmat[k][c];
            for (int i = 0; i < k; ++i) {
#if TRSM_FMA
                bmat[i][c] = __builtin_fmaf(a[i][k], -bk, bmat[i][c]);
#else
                bmat[i][c] = bmat[i][c] - a[i][k] * bk;
#endif
            }
        }
    }

    for (int i = 0; i < 3; ++i)
        for (int j = 0; j < 4; ++j)
            out[i * 4 + j] = bmat[i][j];

    out[12] = K[0];  // fx
    out[13] = K[4];  // fy
    out[14] = K[2];  // cx
    out[15] = K[5];  // cy
}

__global__ void prep_cams_f32(const float* __restrict__ intr,
                              const float* __restrict__ c2e,
                              float* __restrict__ cams) {
    int idx = blockIdx.x * blockDim.x + threadIdx.x;
    if (idx >= NIMG) return;
    inv4_sgesv(c2e + idx * 16, intr + idx * 9, cams + idx * 16);
}

// ---------------------------------------------------------------------------
// Projection + closed-form binning. fp contract(off) INSIDE (R7 lesson).
// Bit-exact vs numpy f32 pipeline (validated absmax 0, R4-R10).
// ---------------------------------------------------------------------------
__device__ __forceinline__ bool project_pair(const float* M, float px, float py,
                                             float pz, float lo, float hi,
                                             int& pix, int& label) {
#pragma clang fp contract(off)
    // numpy einsum tail: accum=0; j=3,2,1,0; separate mul/add (no FMA)
    float x = M[3];  x = x + M[2]  * pz;  x = x + M[1] * py;  x = x + M[0] * px;
    float y = M[7];  y = y + M[6]  * pz;  y = y + M[5] * py;  y = y + M[4] * px;
    float z = M[11]; z = z + M[10] * pz;  z = z + M[9] * py;  z = z + M[8] * px;

    float zc = fmaxf(z, 1e-6f);
    float u = M[12] * (x / zc) + M[14];   // IEEE div, then mul, then add
    float v = M[13] * (y / zc) + M[15];

    bool ok = (z > 0.1f) && (u >= 0.0f) && (u <= 703.0f) &&
              (v >= 0.0f) && (v <= 255.0f);

    int uf = (int)floorf(u / 4.0f);       // exact pow2 scale; in [0,175]
    int vf = (int)floorf(v / 4.0f);       // in [0,63]
    pix = vf * WF + uf;

    // closed-form searchsorted: d-0.5f exact for d in [0.501,48.499]
    float d = fminf(fmaxf(z, lo), hi);
    label = (int)ceilf(d - 0.5f) - 1;     // in [0,47]
    return ok;
}

// ---------------------------------------------------------------------------
// Kernel: image-major LDS z-buffer, 4-way unrolled point loop (R10 shape:
// wave-uniform global M -> s_load, zero scratch, low VGPR). Block (g, img)
// scans point-chunk g of batch img/6 against camera img%6.
// LDS 45 KB -> 2 blocks/CU (91 KB of 160); G=21 -> 504 blocks <= 512
// residency slots -> 32 waves/CU (hardware occupancy cap).
// ---------------------------------------------------------------------------
__global__ __launch_bounds__(1024)
void scatter_lds(const float4* __restrict__ pts,
                 const float* __restrict__ cams,
                 const float* __restrict__ edges_f,
                 uint8_t* __restrict__ reps,
                 int npts, int csz) {
    __shared__ unsigned sbuf[IMGPIX];          // 45056 B

    int g   = blockIdx.x;
    int img = blockIdx.y;                      // b*6 + n
    int b   = img / NCAM;

    for (int i = threadIdx.x; i < IMGPIX; i += 1024)
        sbuf[i] = 0xFFFFFFFFu;
    __syncthreads();

    const float* M = cams + img * 16;          // wave-uniform -> scalar loads
    float lo = edges_f[0]         + 0.001f;
    float hi = edges_f[NEDGE - 1] - 0.001f;

    int start = g * csz;
    int end   = start + csz; if (end > npts) end = npts;
    const float4* bp = pts + (size_t)b * npts;

    int p = start + (int)threadIdx.x;

    // main: 4 independent projection pipelines per thread (covers div chains)
    for (; p + 3 * 1024 < end; p += 4 * 1024) {
        float4 a0 = bp[p];
        float4 a1 = bp[p + 1024];
        float4 a2 = bp[p + 2048];
        float4 a3 = bp[p + 3072];

        int px0, l0, px1, l1, px2, l2, px3, l3;
        bool k0 = project_pair(M, a0.x, a0.y, a0.z, lo, hi, px0, l0);
        bool k1 = project_pair(M, a1.x, a1.y, a1.z, lo, hi, px1, l1);
        bool k2 = project_pair(M, a2.x, a2.y, a2.z, lo, hi, px2, l2);
        bool k3 = project_pair(M, a3.x, a3.y, a3.z, lo, hi, px3, l3);

        if (k0) atomicMin(&sbuf[px0], (unsigned)l0);
        if (k1) atomicMin(&sbuf[px1], (unsigned)l1);
        if (k2) atomicMin(&sbuf[px2], (unsigned)l2);
        if (k3) atomicMin(&sbuf[px3], (unsigned)l3);
    }
    // remainder
    for (; p < end; p += 1024) {
        float4 a0 = bp[p];
        int px0, l0;
        if (project_pair(M, a0.x, a0.y, a0.z, lo, hi, px0, l0))
            atomicMin(&sbuf[px0], (unsigned)l0);
    }
    __syncthreads();

    uint8_t* r = reps + (size_t)g * NPIX + (size_t)img * IMGPIX;
    for (int i = threadIdx.x; i < IMGPIX; i += 1024)
        r[i] = (uint8_t)sbuf[i];               // 255 = empty, else label
}

// ---------------------------------------------------------------------------
// Kernel: merge G replicas, 4 pixels/thread via uint loads (NPIX % 4 == 0).
// ---------------------------------------------------------------------------
__global__ void merge_reps(const uint8_t* __restrict__ reps, int G,
                           int* __restrict__ out) {
    int q = blockIdx.x * blockDim.x + threadIdx.x;   // quad index
    if (q >= NPIX / 4) return;

    unsigned m = 0xFFFFFFFFu;                        // per-byte min, start 255
    for (int g = 0; g < G; ++g) {
        unsigned v = *(const unsigned*)(reps + (size_t)g * NPIX + q * 4);
        // byte-wise min(m, v)
        unsigned lo0 = (m & 0xFFu),        v0 = (v & 0xFFu);
        unsigned lo1 = (m >> 8) & 0xFFu,   v1 = (v >> 8) & 0xFFu;
        unsigned lo2 = (m >> 16) & 0xFFu,  v2 = (v >> 16) & 0xFFu;
        unsigned lo3 = (m >> 24),          v3 = (v >> 24);
        lo0 = v0 < lo0 ? v0 : lo0;
        lo1 = v1 < lo1 ? v1 : lo1;
        lo2 = v2 < lo2 ? v2 : lo2;
        lo3 = v3 < lo3 ? v3 : lo3;
        m = lo0 | (lo1 << 8) | (lo2 << 16) | (lo3 << 24);
    }
    int4 r;
    unsigned b0 = m & 0xFFu, b1 = (m >> 8) & 0xFFu,
             b2 = (m >> 16) & 0xFFu, b3 = m >> 24;
    r.x = (b0 == 255u) ? -1 : (int)b0;
    r.y = (b1 == 255u) ? -1 : (int)b1;
    r.z = (b2 == 255u) ? -1 : (int)b2;
    r.w = (b3 == 255u) ? -1 : (int)b3;
    ((int4*)out)[q] = r;
}

// ---------------------------------------------------------------------------
// Fallback path (validated R5 semantics) for tiny workspaces.
// ---------------------------------------------------------------------------
__global__ __launch_bounds__(256)
void scatter_minbin(const float4* __restrict__ pts,
                    const float* __restrict__ cams,
                    const float* __restrict__ edges_f,
                    int* __restrict__ out,
                    int npts) {
    int p = blockIdx.x * blockDim.x + threadIdx.x;
    int b = blockIdx.y;
    if (p >= npts) return;

    float4 pt = pts[(size_t)b * npts + p];
    float lo = edges_f[0]         + 0.001f;
    float hi = edges_f[NEDGE - 1] - 0.001f;

#pragma unroll
    for (int n = 0; n < NCAM; ++n) {
        const float* M = cams + (b * NCAM + n) * 16;
        int pix, label;
        if (project_pair(M, pt.x, pt.y, pt.z, lo, hi, pix, label)) {
            atomicMin(&out[(b * NCAM + n) * IMGPIX + pix], label);
        }
    }
}

__global__ void finalize(int* out) {
    int i = blockIdx.x * blockDim.x + threadIdx.x;
    if (i < NPIX && out[i] == SENTINEL) out[i] = -1;
}

// ---------------------------------------------------------------------------
extern "C" void kernel_launch(void* const* d_in, const int* in_sizes, int n_in,
                              void* d_out, int out_size, void* d_ws, size_t ws_size,
                              hipStream_t stream) {
    const float* points    = (const float*)d_in[0];  // (B, Npts, 4) f32
    const float* intrinsic = (const float*)d_in[1];  // (B, Ncam, 3, 3) f32
    const float* cam2ego   = (const float*)d_in[2];  // (B, Ncam, 4, 4) f32
    const float* edges     = (const float*)d_in[3];  // (49,) f32

    int npts = in_sizes[0] / (BB * 4);               // 500000
    int* out = (int*)d_out;

    float*   cams = (float*)d_ws;                    // 1.5 KB at offset 0
    uint8_t* reps = (uint8_t*)d_ws + 2048;           // G replica sets of NPIX u8

    // G = 21 -> 504 blocks -> 2 blocks/CU (32 waves/CU = HW cap), <= 512 slots
    int G = 0;
    if (ws_size > 2048 + (size_t)NPIX)
        G = (int)((ws_size - 2048) / (size_t)NPIX);
    if (G > 21) G = 21;

    prep_cams_f32<<<1, 64, 0, stream>>>(intrinsic, cam2ego, cams);

    if (G >= 1) {
        int csz = (npts + G - 1) / G;
        dim3 grid(G, NIMG);
        scatter_lds<<<grid, 1024, 0, stream>>>((const float4*)points, cams,
                                               edges, reps, npts, csz);
        merge_reps<<<(NPIX / 4 + 255) / 256, 256, 0, stream>>>(reps, G, out);
    } else {
        // tiny-workspace fallback: validated R5 path
        hipMemsetAsync(out, 0x7F, (size_t)NPIX * sizeof(int), stream);
        dim3 grid((npts + 255) / 256, BB);
        scatter_minbin<<<grid, 256, 0, stream>>>((const float4*)points, cams,
                                                 edges, out, npts);
        finalize<<<(NPIX + 255) / 256, 256, 0, stream>>>(out);
    }
}

// Round 12
// 41.429 us; speedup vs baseline: 1.1786x; 1.1786x over previous
//
#include <hip/hip_runtime.h>
#include <stdint.h>

// Problem constants (from setup_inputs in the reference)
#define BB    4
#define NCAM  6
#define HF    64
#define WF    176
#define IMGPIX (HF * WF)               // 11264
#define NIMG  (BB * NCAM)              // 24
#define NPIX  (NIMG * IMGPIX)          // 270336
#define NEDGE 49
#define SENTINEL 0x7F7F7F7F            // fallback path: memset-able, > any label

// ---- f32-semantics toggles (validated: absmax 0 in rounds 4-11) ----
#define GER_FMA     1
#define TRSM_RECIP  1
#define TRSM_FMA    1

// ---------------------------------------------------------------------------
// np.linalg.inv(float32) emulation = LAPACK sgesv(A, I). Validated bit-exact
// (absmax 0, R4-R11). fp contract(off) INSIDE the function (lexically scoped;
// R7 lesson). Runs only in the tiny 24-thread prep kernel — its
// runtime-indexed arrays (scratch) must stay OUT of the hot kernel (R9 lesson).
// ---------------------------------------------------------------------------
__device__ void inv4_sgesv(const float* __restrict__ m,   // 4x4 cam2ego
                           const float* __restrict__ K,   // 3x3 intrinsics
                           float* __restrict__ out) {     // 16 floats
#pragma clang fp contract(off)
    float a[4][4];
    for (int i = 0; i < 4; ++i)
        for (int j = 0; j < 4; ++j)
            a[i][j] = m[i * 4 + j];

    // ---- sgetf2: right-looking LU with partial pivoting ----
    int ipiv[4];
    for (int j = 0; j < 4; ++j) {
        int p = j;
        float best = fabsf(a[j][j]);
        for (int i = j + 1; i < 4; ++i) {
            float v = fabsf(a[i][j]);
            if (v > best) { best = v; p = i; }
        }
        ipiv[j] = p;
        if (p != j) {
            for (int k = 0; k < 4; ++k) {
                float t = a[j][k]; a[j][k] = a[p][k]; a[p][k] = t;
            }
        }
        float r = 1.0f / a[j][j];
        for (int i = j + 1; i < 4; ++i) a[i][j] = a[i][j] * r;
        for (int k = j + 1; k < 4; ++k) {
            float temp = -a[j][k];
            for (int i = j + 1; i < 4; ++i) {
#if GER_FMA
                a[i][k] = __builtin_fmaf(a[i][j], temp, a[i][k]);
#else
                a[i][k] = a[i][k] + a[i][j] * temp;
#endif
            }
        }
    }

    // ---- sgetrs on B = I ----
    float bmat[4][4];
    for (int i = 0; i < 4; ++i)
        for (int j = 0; j < 4; ++j)
            bmat[i][j] = (i == j) ? 1.0f : 0.0f;

    for (int k = 0; k < 4; ++k) {
        int p = ipiv[k];
        if (p != k) {
            for (int c = 0; c < 4; ++c) {
                float t = bmat[k][c]; bmat[k][c] = bmat[p][c]; bmat[p][c] = t;
            }
        }
    }

    // trsm: Left, Lower, NoTrans, Unit
    for (int c = 0; c < 4; ++c) {
        for (int k = 0; k < 4; ++k) {
            float bk = bmat[k][c];
            for (int i = k + 1; i < 4; ++i) {
#if TRSM_FMA
                bmat[i][c] = __builtin_fmaf(a[i][k], -bk, bmat[i][c]);
#else
                bmat[i][c] = bmat[i][c] - a[i][k] * bk;
#endif
            }
        }
    }

    // trsm: Left, Upper, NoTrans, NonUnit (reciprocal diagonal)
#if TRSM_RECIP
    float rdiag[4];
    for (int k = 0; k < 4; ++k) rdiag[k] = 1.0f / a[k][k];
#endif
    for (int c = 0; c < 4; ++c) {
        for (int k = 3; k >= 0; --k) {
#if TRSM_RECIP
            bmat[k][c] = bmat[k][c] * rdiag[k];
#else
            bmat[k][c] = bmat[k][c] / a[k][k];
#endif
            float bk = bmat[k][c];
            for (int i = 0; i < k; ++i) {
#if TRSM_FMA
                bmat[i][c] = __builtin_fmaf(a[i][k], -bk, bmat[i][c]);
#else
                bmat[i][c] = bmat[i][c] - a[i][k] * bk;
#endif
            }
        }
    }

    for (int i = 0; i < 3; ++i)
        for (int j = 0; j < 4; ++j)
            out[i * 4 + j] = bmat[i][j];

    out[12] = K[0];  // fx
    out[13] = K[4];  // fy
    out[14] = K[2];  // cx
    out[15] = K[5];  // cy
}

__global__ void prep_cams_f32(const float* __restrict__ intr,
                              const float* __restrict__ c2e,
                              float* __restrict__ cams) {
    int idx = blockIdx.x * blockDim.x + threadIdx.x;
    if (idx >= NIMG) return;
    inv4_sgesv(c2e + idx * 16, intr + idx * 9, cams + idx * 16);
}

// ---------------------------------------------------------------------------
// Projection + closed-form binning. fp contract(off) INSIDE (R7 lesson).
// Bit-exact vs numpy f32 pipeline (validated absmax 0, R4-R11).
// uf/vf use trunc (cvt_i32) instead of floorf: for the ok-guarded range
// u in [0,703], v in [0,255] trunc == floor (exact *0.25f pow2 scale); when
// !ok, pix is never used, so garbage trunc results are harmless.
// ---------------------------------------------------------------------------
__device__ __forceinline__ bool project_pair(const float* M, float px, float py,
                                             float pz, float lo, float hi,
                                             int& pix, int& label) {
#pragma clang fp contract(off)
    // numpy einsum tail: accum=0; j=3,2,1,0; separate mul/add (no FMA)
    float x = M[3];  x = x + M[2]  * pz;  x = x + M[1] * py;  x = x + M[0] * px;
    float y = M[7];  y = y + M[6]  * pz;  y = y + M[5] * py;  y = y + M[4] * px;
    float z = M[11]; z = z + M[10] * pz;  z = z + M[9] * py;  z = z + M[8] * px;

    float zc = fmaxf(z, 1e-6f);
    float u = M[12] * (x / zc) + M[14];   // IEEE div, then mul, then add
    float v = M[13] * (y / zc) + M[15];

    bool ok = (z > 0.1f) && (u >= 0.0f) && (u <= 703.0f) &&
              (v >= 0.0f) && (v <= 255.0f);

    int uf = (int)(u * 0.25f);            // trunc == floor on guarded range
    int vf = (int)(v * 0.25f);
    pix = vf * WF + uf;

    // closed-form searchsorted: d-0.5f exact for d in [0.501,48.499]
    float d = fminf(fmaxf(z, lo), hi);
    label = (int)ceilf(d - 0.5f) - 1;     // in [0,47]
    return ok;
}

// ---------------------------------------------------------------------------
// Kernel: image-major LDS z-buffer, 8-way unrolled point loop (R10 shape:
// wave-uniform global M -> s_load, zero scratch; G=10 -> 240 blocks ->
// 1 block/CU, empirically optimal — 2 blocks/CU regressed in R9 AND R11).
// 8 independent projection pipelines/thread cover the IEEE-div chains;
// VGPR budget is free up to 128 at this grid-limited occupancy.
// ---------------------------------------------------------------------------
__global__ __launch_bounds__(1024)
void scatter_lds(const float4* __restrict__ pts,
                 const float* __restrict__ cams,
                 const float* __restrict__ edges_f,
                 uint8_t* __restrict__ reps,
                 int npts, int csz) {
    __shared__ unsigned sbuf[IMGPIX];          // 45056 B

    int g   = blockIdx.x;
    int img = blockIdx.y;                      // b*6 + n
    int b   = img / NCAM;

    for (int i = threadIdx.x; i < IMGPIX; i += 1024)
        sbuf[i] = 0xFFFFFFFFu;
    __syncthreads();

    const float* M = cams + img * 16;          // wave-uniform -> scalar loads
    float lo = edges_f[0]         + 0.001f;
    float hi = edges_f[NEDGE - 1] - 0.001f;

    int start = g * csz;
    int end   = start + csz; if (end > npts) end = npts;
    const float4* bp = pts + (size_t)b * npts;

    int p = start + (int)threadIdx.x;

    // main: 8 independent projection pipelines per thread
    for (; p + 7 * 1024 < end; p += 8 * 1024) {
        float4 a0 = bp[p];
        float4 a1 = bp[p + 1024];
        float4 a2 = bp[p + 2048];
        float4 a3 = bp[p + 3072];
        float4 a4 = bp[p + 4096];
        float4 a5 = bp[p + 5120];
        float4 a6 = bp[p + 6144];
        float4 a7 = bp[p + 7168];

        int px0, l0, px1, l1, px2, l2, px3, l3;
        int px4, l4, px5, l5, px6, l6, px7, l7;
        bool k0 = project_pair(M, a0.x, a0.y, a0.z, lo, hi, px0, l0);
        bool k1 = project_pair(M, a1.x, a1.y, a1.z, lo, hi, px1, l1);
        bool k2 = project_pair(M, a2.x, a2.y, a2.z, lo, hi, px2, l2);
        bool k3 = project_pair(M, a3.x, a3.y, a3.z, lo, hi, px3, l3);
        bool k4 = project_pair(M, a4.x, a4.y, a4.z, lo, hi, px4, l4);
        bool k5 = project_pair(M, a5.x, a5.y, a5.z, lo, hi, px5, l5);
        bool k6 = project_pair(M, a6.x, a6.y, a6.z, lo, hi, px6, l6);
        bool k7 = project_pair(M, a7.x, a7.y, a7.z, lo, hi, px7, l7);

        if (k0) atomicMin(&sbuf[px0], (unsigned)l0);
        if (k1) atomicMin(&sbuf[px1], (unsigned)l1);
        if (k2) atomicMin(&sbuf[px2], (unsigned)l2);
        if (k3) atomicMin(&sbuf[px3], (unsigned)l3);
        if (k4) atomicMin(&sbuf[px4], (unsigned)l4);
        if (k5) atomicMin(&sbuf[px5], (unsigned)l5);
        if (k6) atomicMin(&sbuf[px6], (unsigned)l6);
        if (k7) atomicMin(&sbuf[px7], (unsigned)l7);
    }
    // remainder
    for (; p < end; p += 1024) {
        float4 a0 = bp[p];
        int px0, l0;
        if (project_pair(M, a0.x, a0.y, a0.z, lo, hi, px0, l0))
            atomicMin(&sbuf[px0], (unsigned)l0);
    }
    __syncthreads();

    // writeback: pack 4 labels -> u32, 2816 coalesced dword stores
    unsigned* r32 = (unsigned*)(reps + (size_t)g * NPIX + (size_t)img * IMGPIX);
    for (int i = threadIdx.x; i < IMGPIX / 4; i += 1024) {
        unsigned w = (sbuf[4 * i] & 0xFFu)
                   | ((sbuf[4 * i + 1] & 0xFFu) << 8)
                   | ((sbuf[4 * i + 2] & 0xFFu) << 16)
                   | ((sbuf[4 * i + 3] & 0xFFu) << 24);
        r32[i] = w;                            // 255 = empty, else label
    }
}

// ---------------------------------------------------------------------------
// Kernel: merge G replicas, 4 pixels/thread via uint loads (NPIX % 4 == 0).
// Validated absmax 0 in R11.
// ---------------------------------------------------------------------------
__global__ void merge_reps(const uint8_t* __restrict__ reps, int G,
                           int* __restrict__ out) {
    int q = blockIdx.x * blockDim.x + threadIdx.x;   // quad index
    if (q >= NPIX / 4) return;

    unsigned m = 0xFFFFFFFFu;                        // per-byte min, start 255
    for (int g = 0; g < G; ++g) {
        unsigned v = *(const unsigned*)(reps + (size_t)g * NPIX + q * 4);
        unsigned lo0 = (m & 0xFFu),        v0 = (v & 0xFFu);
        unsigned lo1 = (m >> 8) & 0xFFu,   v1 = (v >> 8) & 0xFFu;
        unsigned lo2 = (m >> 16) & 0xFFu,  v2 = (v >> 16) & 0xFFu;
        unsigned lo3 = (m >> 24),          v3 = (v >> 24);
        lo0 = v0 < lo0 ? v0 : lo0;
        lo1 = v1 < lo1 ? v1 : lo1;
        lo2 = v2 < lo2 ? v2 : lo2;
        lo3 = v3 < lo3 ? v3 : lo3;
        m = lo0 | (lo1 << 8) | (lo2 << 16) | (lo3 << 24);
    }
    int4 r;
    unsigned b0 = m & 0xFFu, b1 = (m >> 8) & 0xFFu,
             b2 = (m >> 16) & 0xFFu, b3 = m >> 24;
    r.x = (b0 == 255u) ? -1 : (int)b0;
    r.y = (b1 == 255u) ? -1 : (int)b1;
    r.z = (b2 == 255u) ? -1 : (int)b2;
    r.w = (b3 == 255u) ? -1 : (int)b3;
    ((int4*)out)[q] = r;
}

// ---------------------------------------------------------------------------
// Fallback path (validated R5 semantics) for tiny workspaces.
// ---------------------------------------------------------------------------
__global__ __launch_bounds__(256)
void scatter_minbin(const float4* __restrict__ pts,
                    const float* __restrict__ cams,
                    const float* __restrict__ edges_f,
                    int* __restrict__ out,
                    int npts) {
    int p = blockIdx.x * blockDim.x + threadIdx.x;
    int b = blockIdx.y;
    if (p >= npts) return;

    float4 pt = pts[(size_t)b * npts + p];
    float lo = edges_f[0]         + 0.001f;
    float hi = edges_f[NEDGE - 1] - 0.001f;

#pragma unroll
    for (int n = 0; n < NCAM; ++n) {
        const float* M = cams + (b * NCAM + n) * 16;
        int pix, label;
        if (project_pair(M, pt.x, pt.y, pt.z, lo, hi, pix, label)) {
            atomicMin(&out[(b * NCAM + n) * IMGPIX + pix], label);
        }
    }
}

__global__ void finalize(int* out) {
    int i = blockIdx.x * blockDim.x + threadIdx.x;
    if (i < NPIX && out[i] == SENTINEL) out[i] = -1;
}

// ---------------------------------------------------------------------------
extern "C" void kernel_launch(void* const* d_in, const int* in_sizes, int n_in,
                              void* d_out, int out_size, void* d_ws, size_t ws_size,
                              hipStream_t stream) {
    const float* points    = (const float*)d_in[0];  // (B, Npts, 4) f32
    const float* intrinsic = (const float*)d_in[1];  // (B, Ncam, 3, 3) f32
    const float* cam2ego   = (const float*)d_in[2];  // (B, Ncam, 4, 4) f32
    const float* edges     = (const float*)d_in[3];  // (49,) f32

    int npts = in_sizes[0] / (BB * 4);               // 500000
    int* out = (int*)d_out;

    float*   cams = (float*)d_ws;                    // 1.5 KB at offset 0
    uint8_t* reps = (uint8_t*)d_ws + 2048;           // G replica sets of NPIX u8

    // G = 10 -> 240 blocks -> 1 block/CU (R10-validated optimum; 2 blocks/CU
    // regressed in both R9 and R11).
    int G = 0;
    if (ws_size > 2048 + (size_t)NPIX)
        G = (int)((ws_size - 2048) / (size_t)NPIX);
    if (G > 10) G = 10;

    prep_cams_f32<<<1, 64, 0, stream>>>(intrinsic, cam2ego, cams);

    if (G >= 1) {
        int csz = (npts + G - 1) / G;
        dim3 grid(G, NIMG);
        scatter_lds<<<grid, 1024, 0, stream>>>((const float4*)points, cams,
                                               edges, reps, npts, csz);
        merge_reps<<<(NPIX / 4 + 255) / 256, 256, 0, stream>>>(reps, G, out);
    } else {
        // tiny-workspace fallback: validated R5 path
        hipMemsetAsync(out, 0x7F, (size_t)NPIX * sizeof(int), stream);
        dim3 grid((npts + 255) / 256, BB);
        scatter_minbin<<<grid, 256, 0, stream>>>((const float4*)points, cams,
                                                 edges, out, npts);
        finalize<<<(NPIX + 255) / 256, 256, 0, stream>>>(out);
    }
}